// Round 4
// baseline (629.289 us; speedup 1.0000x reference)
//
#include <hip/hip_runtime.h>

typedef _Float16 f16;
typedef f16 f16x8 __attribute__((ext_vector_type(8)));
typedef f16 f16x4 __attribute__((ext_vector_type(4)));
typedef float f32x4 __attribute__((ext_vector_type(4)));

#define MFMA16(a,b,c) __builtin_amdgcn_mfma_f32_16x16x32_f16((a),(b),(c),0,0,0)

static __device__ __forceinline__ f16x8 ld8(const f16* p){ return *(const f16x8*)p; }
static __device__ __forceinline__ float sigm(float x){ return 1.f/(1.f + __expf(-x)); }

// ---------------------------------------------------------------------------
// Weight prep: fold gammas, cast fp16, store transposed (N rows x K cols) so
// fragments are contiguous 16B along K. Colsums of Wsl/Wss (for the raw-s
// gate un-normalization) are 4-way parallel + shuffle-reduced.
// ---------------------------------------------------------------------------
__global__ __launch_bounds__(256) void k_prep(
    const float* __restrict__ apb_gamma, const float* __restrict__ apb_Wg, const float* __restrict__ apb_Wskip,
    const float* __restrict__ ct_gamma,  const float* __restrict__ ct_Wg,  const float* __restrict__ ct_Wskip,
    const float* __restrict__ Wq, const float* __restrict__ Wk, const float* __restrict__ Wv, const float* __restrict__ Wgate,
    const float* __restrict__ Wsl, const float* __restrict__ Wss,
    const float* __restrict__ Wa1, const float* __restrict__ Wa2,
    const float* __restrict__ Wo, const float* __restrict__ Wb,
    const float* __restrict__ gamma_z, const float* __restrict__ Wz,
    f16* __restrict__ wA, f16* __restrict__ wC, f16* __restrict__ wQK, f16* __restrict__ wVG,
    f16* __restrict__ wSG, f16* __restrict__ wAB, f16* __restrict__ wO, f16* __restrict__ wBt,
    float* __restrict__ wzg, float* __restrict__ Slv, float* __restrict__ Ssv)
{
  const int t0 = blockIdx.x*256 + threadIdx.x;
  const int stride = gridDim.x*256;
  for (int i = t0; i < 256*128; i += stride){
    const int n = i >> 7, k = i & 127;
    const int m = n & 127;
    wA[i]  = (f16)(((n<128) ? apb_Wg[k*128+m] : apb_Wskip[k*128+m]) * apb_gamma[k]);
    wC[i]  = (f16)(((n<128) ? ct_Wg[k*128+m]  : ct_Wskip[k*128+m])  * ct_gamma[k]);
    wQK[i] = (f16)((n<128) ? Wq[k*128+m] : Wk[k*128+m]);
    wVG[i] = (f16)((n<128) ? Wv[k*128+m] : Wgate[k*128+m]);
    wSG[i] = (f16)((n<128) ? Wsl[k*128+m] : Wss[k*128+m]);
  }
  for (int i = t0; i < 512*128; i += stride){
    const int n = i >> 7, k = i & 127;
    wAB[i] = (f16)((n < 256) ? Wa1[k*256 + n] : Wa2[k*256 + (n-256)]);
  }
  for (int i = t0; i < 128*128; i += stride){
    const int n = i >> 7, k = i & 127;
    wO[i] = (f16)Wo[k*128+n];
  }
  for (int i = t0; i < 128*256; i += stride){
    const int n = i >> 8, k = i & 255;
    wBt[i] = (f16)Wb[k*128+n];
  }
  if (t0 < 64) wzg[t0] = gamma_z[t0 & 15] * Wz[(t0 & 15)*4 + (t0 >> 4)];
  if (t0 < 1024){
    const int mat = t0 >> 9;               // 0: Wsl, 1: Wss
    const int j = t0 & 511;
    const int cc = j >> 2, part = j & 3;   // 4 threads per column
    const float* Wp = mat ? Wss : Wsl;
    float acc = 0.f;
    #pragma unroll 4
    for (int k = part*32; k < part*32 + 32; k++) acc += Wp[k*128 + cc];
    acc += __shfl_xor(acc, 1);
    acc += __shfl_xor(acc, 2);
    if (part == 0){ if (mat) Ssv[cc] = acc; else Slv[cc] = acc; }
  }
}

// ---------------------------------------------------------------------------
// MEGA-FUSED pre-attention kernel WITH role-split z-bias streaming.
// Grid 3072: blocks %3==0 (1024) run the adaLN/QKVG/T/gates pipeline on 32
// rows each; the other 2048 blocks stream z -> LN -> @(gamma_z*Wz) and write
// the f16 bias tensor [tile][h][q][k]. The bias work is BW-bound and
// independent of a/s, so it overlaps the latency-bound pre phases.
// ---------------------------------------------------------------------------
__global__ __launch_bounds__(256, 4) void k_pre(
    const float* __restrict__ A, const float* __restrict__ S,
    const float* __restrict__ Z, const float* __restrict__ WZG,
    const f16* __restrict__ wA, const f16* __restrict__ wC,
    const f16* __restrict__ wQK, const f16* __restrict__ wVG,
    const f16* __restrict__ wSG, const f16* __restrict__ wAB,
    const float* __restrict__ bgA, const float* __restrict__ bgC,
    const float* __restrict__ bq, const float* __restrict__ bsl, const float* __restrict__ bss,
    const float* __restrict__ Slv, const float* __restrict__ Ssv,
    f16* __restrict__ Qo, f16* __restrict__ Ko, f16* __restrict__ Vt, f16* __restrict__ Go,
    f16* __restrict__ T, f16* __restrict__ GL, f16* __restrict__ GS,
    f16* __restrict__ BiasG)
{
  __shared__ f16 lsn[32*136];
  __shared__ f16 lan[32*136];   // holds a_n in phase 2, then becomes a3
  __shared__ f16 la1[32*136];
  __shared__ float lsm[32], lsd[32];
  __shared__ float wzs[64];
  const int tid = threadIdx.x;

  if (blockIdx.x % 3 != 0){
    // ---------------- bias role: 2048 blocks x 256 threads x 8 items -------
    const int bb = blockIdx.x - blockIdx.x/3 - 1;   // 0..2047
    if (tid < 64) wzs[tid] = WZG[tid];
    __syncthreads();
    #pragma unroll
    for (int it = 0; it < 8; it++){
      const int i = bb*2048 + it*256 + tid;         // item: (t, qq, kk)
      const float* zp = Z + (size_t)i*16;
      const float4 z0 = *(const float4*)(zp);
      const float4 z1 = *(const float4*)(zp + 4);
      const float4 z2 = *(const float4*)(zp + 8);
      const float4 z3 = *(const float4*)(zp + 12);
      const float xs[16] = {z0.x,z0.y,z0.z,z0.w, z1.x,z1.y,z1.z,z1.w,
                            z2.x,z2.y,z2.z,z2.w, z3.x,z3.y,z3.z,z3.w};
      float sm = 0.f, sq = 0.f;
      #pragma unroll
      for (int cc = 0; cc < 16; cc++){ sm += xs[cc]; sq += xs[cc]*xs[cc]; }
      const float mean = sm*(1.f/16.f);
      const float var  = sq*(1.f/16.f) - mean*mean;
      const float rs   = rsqrtf(var + 1e-5f);
      const size_t tb4 = (size_t)(i >> 12) * 4;
      const int qk = i & 4095;
      #pragma unroll
      for (int h = 0; h < 4; h++){
        float acc = 0.f;
        #pragma unroll
        for (int cc = 0; cc < 16; cc++) acc += (xs[cc]-mean)*wzs[h*16+cc];
        BiasG[(tb4 + h)*4096 + qk] = (f16)(acc*rs);
      }
    }
    return;
  }
  // ------------------ pre role: 1024 blocks, 32 rows each -------------------
  const size_t rbase = (size_t)(blockIdx.x/3) * 32;

  // ---- Phase 1: LN(s) on threads 0-127, LN(a) on threads 128-255 ----
  {
    const int half = tid >> 7;
    const int row = (tid & 127) >> 2, part = tid & 3;
    const size_t gr = rbase + row;
    const float* p = (half ? A : S) + gr*128 + part*32;
    float v[32];
    #pragma unroll
    for (int j = 0; j < 8; j++){
      const float4 t4 = ((const float4*)p)[j];
      v[j*4+0]=t4.x; v[j*4+1]=t4.y; v[j*4+2]=t4.z; v[j*4+3]=t4.w;
    }
    float sm = 0.f, sq = 0.f;
    #pragma unroll
    for (int j = 0; j < 32; j++){ sm += v[j]; sq += v[j]*v[j]; }
    sm += __shfl_xor(sm,1); sq += __shfl_xor(sq,1);
    sm += __shfl_xor(sm,2); sq += __shfl_xor(sq,2);
    const float mean = sm*(1.f/128.f);
    const float var  = sq*(1.f/128.f) - mean*mean;
    const float rstd = rsqrtf(var + 1e-5f);
    if (!half && part == 0){ lsm[row] = mean; lsd[row] = (var + 1e-5f)*rstd; }  // std
    f16* dst = half ? lan : lsn;
    #pragma unroll
    for (int j = 0; j < 4; j++){
      f16x8 o;
      #pragma unroll
      for (int e = 0; e < 8; e++) o[e] = (f16)((v[j*8+e]-mean)*rstd);
      *(f16x8*)&dst[row*136 + part*32 + j*8] = o;
    }
  }
  __syncthreads();

  const int l = tid & 63, w = tid >> 6;
  const int c = l & 15, q4 = l >> 4;

  // ---- Phase 2: dual adaLN ----
  #pragma unroll
  for (int jj = 0; jj < 2; jj++){
    const int n0 = (jj*4 + w)*16;
    #pragma unroll
    for (int mat = 0; mat < 2; mat++){
      const f16* W = mat ? wC : wA;
      f16x8 b0[4], b1[4];
      #pragma unroll
      for (int kc = 0; kc < 4; kc++){
        b0[kc] = ld8(W + (size_t)(n0 + c)*128 + kc*32 + q4*8);
        b1[kc] = ld8(W + (size_t)(128 + n0 + c)*128 + kc*32 + q4*8);
      }
      const float4 bv = *(const float4*)((mat ? bgC : bgA) + n0 + q4*4);
      const float bvr[4] = {bv.x, bv.y, bv.z, bv.w};
      f16* dst = mat ? lan : la1;
      #pragma unroll
      for (int mi = 0; mi < 2; mi++){
        f32x4 d0 = {0,0,0,0}, d1 = {0,0,0,0};
        #pragma unroll
        for (int kc = 0; kc < 4; kc++){
          const f16x8 av = *(const f16x8*)&lsn[(mi*16 + c)*136 + kc*32 + q4*8];
          d0 = MFMA16(b0[kc], av, d0);
          d1 = MFMA16(b1[kc], av, d1);
        }
        const int row = mi*16 + c;
        const f16x4 anv = *(const f16x4*)&lan[row*136 + n0 + q4*4];
        f16x4 o;
        #pragma unroll
        for (int r = 0; r < 4; r++)
          o[r] = (f16)(sigm(d0[r] + bvr[r])*(float)anv[r] + d1[r]);
        *(f16x4*)&dst[row*136 + n0 + q4*4] = o;
      }
    }
  }
  __syncthreads();

  const int bidx = (int)(rbase >> 14);
  const int ntk0 = (int)(rbase & 16383);

  // ---- Phase 3a: QKVG from a1 (V unswapped -> transposed f16x4 store) ----
  #pragma unroll
  for (int jj = 0; jj < 2; jj++){
    const int n0 = (jj*4 + w)*16;
    { // Q,K
      f16x8 bQ[4], bK[4];
      #pragma unroll
      for (int kc = 0; kc < 4; kc++){
        bQ[kc] = ld8(wQK + (size_t)(n0 + c)*128 + kc*32 + q4*8);
        bK[kc] = ld8(wQK + (size_t)(128 + n0 + c)*128 + kc*32 + q4*8);
      }
      const float4 bv = *(const float4*)(bq + n0 + q4*4);
      const float bvr[4] = {bv.x, bv.y, bv.z, bv.w};
      #pragma unroll
      for (int mi = 0; mi < 2; mi++){
        f32x4 dQ = {0,0,0,0}, dK = {0,0,0,0};
        #pragma unroll
        for (int kc = 0; kc < 4; kc++){
          const f16x8 av = *(const f16x8*)&la1[(mi*16 + c)*136 + kc*32 + q4*8];
          dQ = MFMA16(bQ[kc], av, dQ);
          dK = MFMA16(bK[kc], av, dK);
        }
        const size_t grow = rbase + mi*16 + c;
        f16x4 qo, ko;
        #pragma unroll
        for (int r = 0; r < 4; r++){
          qo[r] = (f16)((dQ[r] + bvr[r])*0.17677669529663687f);
          ko[r] = (f16)dK[r];
        }
        *(f16x4*)&Qo[grow*128 + n0 + q4*4] = qo;
        *(f16x4*)&Ko[grow*128 + n0 + q4*4] = ko;
      }
    }
    { // V,G
      f16x8 bV[4], bG[4];
      #pragma unroll
      for (int kc = 0; kc < 4; kc++){
        bV[kc] = ld8(wVG + (size_t)(n0 + c)*128 + kc*32 + q4*8);
        bG[kc] = ld8(wVG + (size_t)(128 + n0 + c)*128 + kc*32 + q4*8);
      }
      #pragma unroll
      for (int mi = 0; mi < 2; mi++){
        f32x4 dV = {0,0,0,0}, dG = {0,0,0,0};
        #pragma unroll
        for (int kc = 0; kc < 4; kc++){
          const f16x8 av = *(const f16x8*)&la1[(mi*16 + c)*136 + kc*32 + q4*8];
          dV = MFMA16(av, bV[kc], dV);   // unswapped: lane = (4 tokens x 1 col)
          dG = MFMA16(bG[kc], av, dG);
        }
        const size_t grow = rbase + mi*16 + c;
        f16x4 go;
        #pragma unroll
        for (int r = 0; r < 4; r++) go[r] = (f16)sigm(dG[r]);
        *(f16x4*)&Go[grow*128 + n0 + q4*4] = go;
        f16x4 vv;
        #pragma unroll
        for (int r = 0; r < 4; r++) vv[r] = (f16)dV[r];
        *(f16x4*)(Vt + ((size_t)bidx*128 + n0 + c)*16384 + ntk0 + mi*16 + q4*4) = vv;
      }
    }
  }

  // ---- Phase 3b: transition t = silu(a3@Wa1) * (a3@Wa2) ----
  #pragma unroll
  for (int jj = 0; jj < 4; jj++){
    const int n0t = (jj*4 + w)*16;
    f16x8 b1v[4], b2v[4];
    #pragma unroll
    for (int kc = 0; kc < 4; kc++){
      b1v[kc] = ld8(wAB + (size_t)(n0t + c)*128 + kc*32 + q4*8);
      b2v[kc] = ld8(wAB + (size_t)(256 + n0t + c)*128 + kc*32 + q4*8);
    }
    #pragma unroll
    for (int mi = 0; mi < 2; mi++){
      f32x4 d0 = {0,0,0,0}, d1 = {0,0,0,0};
      #pragma unroll
      for (int kc = 0; kc < 4; kc++){
        const f16x8 av = *(const f16x8*)&lan[(mi*16 + c)*136 + kc*32 + q4*8];  // a3
        d0 = MFMA16(b1v[kc], av, d0);
        d1 = MFMA16(b2v[kc], av, d1);
      }
      const size_t grow = rbase + mi*16 + c;
      f16x4 t4;
      #pragma unroll
      for (int r = 0; r < 4; r++){
        const float u = d0[r];
        t4[r] = (f16)((u*sigm(u))*d1[r]);
      }
      *(f16x4*)&T[grow*256 + n0t + q4*4] = t4;
    }
  }

  // ---- Phase 3c: gates from sn via un-normalization ----
  #pragma unroll
  for (int jj = 0; jj < 2; jj++){
    const int n0 = (jj*4 + w)*16;
    f16x8 b0[4], b1[4];
    #pragma unroll
    for (int kc = 0; kc < 4; kc++){
      b0[kc] = ld8(wSG + (size_t)(n0 + c)*128 + kc*32 + q4*8);
      b1[kc] = ld8(wSG + (size_t)(128 + n0 + c)*128 + kc*32 + q4*8);
    }
    const float4 sl4 = *(const float4*)(Slv + n0 + q4*4);
    const float4 ss4 = *(const float4*)(Ssv + n0 + q4*4);
    const float4 bl4 = *(const float4*)(bsl + n0 + q4*4);
    const float4 bs4 = *(const float4*)(bss + n0 + q4*4);
    const float slr[4] = {sl4.x,sl4.y,sl4.z,sl4.w};
    const float ssr[4] = {ss4.x,ss4.y,ss4.z,ss4.w};
    const float blr[4] = {bl4.x,bl4.y,bl4.z,bl4.w};
    const float bsr[4] = {bs4.x,bs4.y,bs4.z,bs4.w};
    #pragma unroll
    for (int mi = 0; mi < 2; mi++){
      f32x4 d0 = {0,0,0,0}, d1 = {0,0,0,0};
      #pragma unroll
      for (int kc = 0; kc < 4; kc++){
        const f16x8 av = *(const f16x8*)&lsn[(mi*16 + c)*136 + kc*32 + q4*8];
        d0 = MFMA16(b0[kc], av, d0);
        d1 = MFMA16(b1[kc], av, d1);
      }
      const int row = mi*16 + c;
      const size_t grow = rbase + row;
      const float mn = lsm[row], sd = lsd[row];
      f16x4 gl4, gs4;
      #pragma unroll
      for (int r = 0; r < 4; r++){
        gl4[r] = (f16)sigm(d0[r]*sd + mn*slr[r] + blr[r]);
        gs4[r] = (f16)sigm(d1[r]*sd + mn*ssr[r] + bsr[r]);
      }
      *(f16x4*)&GL[grow*128 + n0 + q4*4] = gl4;
      *(f16x4*)&GS[grow*128 + n0 + q4*4] = gs4;
    }
  }
}

// ---------------------------------------------------------------------------
// Fused windowed attention + FINAL epilogue. Bias is precomputed (BiasG),
// read per-lane as f16x4 straight from global: no z phase, no bias staging,
// and P-LDS rows are wave-private -> only 2 barriers total.
// ---------------------------------------------------------------------------
__global__ __launch_bounds__(512) void k_attn(const f16* __restrict__ Q, const f16* __restrict__ K,
    const f16* __restrict__ VT, const f16* __restrict__ BiasG,
    const f16* __restrict__ Go, const f16* __restrict__ T,
    const f16* __restrict__ Wot, const f16* __restrict__ Wbt,
    const f16* __restrict__ GL, const f16* __restrict__ GS, float* __restrict__ out)
{
  __shared__ f16 upb[17408];
  const int tid = threadIdx.x;
  const int b = blockIdx.x >> 9, nb = blockIdx.x & 511;

  const int l = tid & 63, w = tid >> 6;
  const int c = l & 15, q4 = l >> 4;
  const int h = w >> 1, qh = w & 1, m0 = qh*16;
  const f16x8 qf = ld8(Q + ((size_t)b*16384 + (size_t)nb*32 + m0 + c)*128 + h*32 + q4*8);
  const long kbase = (long)b*16384 + (long)nb*32 - 48;
  f32x4 sc[8];
  #pragma unroll
  for (int nt = 0; nt < 8; nt++){
    const f16x8 kf = ld8(K + (kbase + nt*16 + c)*128 + h*32 + q4*8);
    f32x4 zz = {0.f,0.f,0.f,0.f};
    sc[nt] = MFMA16(kf, qf, zz);   // swapped: C[key][query], query = c
  }
  // bias: [tile][h][qq][kk] f16, lane reads its own 4 keys per nt
  const f16* bt = BiasG + (((size_t)(b*512 + nb)*4 + h)*32 + m0 + c)*128;
  #pragma unroll
  for (int nt = 0; nt < 8; nt++){
    const f16x4 bb = *(const f16x4*)&bt[nt*16 + q4*4];
    #pragma unroll
    for (int r = 0; r < 4; r++){
      const long kt = (long)nb*32 - 48 + nt*16 + q4*4 + r;
      const bool inv = (kt < 0) || (kt >= 16384);
      sc[nt][r] = inv ? -1e9f : (sc[nt][r] + (float)bb[r]);
    }
  }
  // softmax over keys for this lane's query (32 in-lane + across 4 q4 groups)
  float mx = sc[0][0];
  #pragma unroll
  for (int nt = 0; nt < 8; nt++)
    #pragma unroll
    for (int r = 0; r < 4; r++) mx = fmaxf(mx, sc[nt][r]);
  mx = fmaxf(mx, __shfl_xor(mx, 16));
  mx = fmaxf(mx, __shfl_xor(mx, 32));
  float sum = 0.f;
  #pragma unroll
  for (int nt = 0; nt < 8; nt++)
    #pragma unroll
    for (int r = 0; r < 4; r++){ const float e = __expf(sc[nt][r]-mx); sc[nt][r] = e; sum += e; }
  sum += __shfl_xor(sum, 16);
  sum += __shfl_xor(sum, 32);
  const float inv = 1.f/sum;
  // P rows (w*16+c) are wave-private: no barrier needed around write+readback
  #pragma unroll
  for (int nt = 0; nt < 8; nt++){
    f16x4 p4;
    #pragma unroll
    for (int r = 0; r < 4; r++) p4[r] = (f16)(sc[nt][r]*inv);
    *(f16x4*)&upb[(w*16 + c)*136 + nt*16 + q4*4] = p4;
  }
  const f16* vb = VT + ((long)b*128)*16384 + (long)nb*32 - 48;
  f32x4 o0 = {0.f,0.f,0.f,0.f}, o1 = {0.f,0.f,0.f,0.f};
  #pragma unroll
  for (int kc = 0; kc < 4; kc++){
    const f16x8 pa = *(const f16x8*)&upb[(w*16 + c)*136 + kc*32 + q4*8];
    const f16x8 v0 = ld8(vb + (long)(h*32 + c)*16384 + kc*32 + q4*8);
    const f16x8 v1 = ld8(vb + (long)(h*32 + 16 + c)*16384 + kc*32 + q4*8);
    o0 = MFMA16(pa, v0, o0);
    o1 = MFMA16(pa, v1, o1);
  }
  __syncthreads();   // all P reads done before o-tile overwrites upb
  // o tile -> LDS as [token][channel], stride 140 (bank-friendly transpose)
  #pragma unroll
  for (int r = 0; r < 4; r++){
    upb[(m0 + q4*4 + r)*140 + h*32 + c]      = (f16)o0[r];
    upb[(m0 + q4*4 + r)*140 + h*32 + 16 + c] = (f16)o1[r];
  }
  __syncthreads();

  // ---- fused final: out = gl*((g.o)@Wo) + gs*(t@Wb), wave w -> ch tile w*16 ----
  const size_t tb = (size_t)b*16384 + (size_t)nb*32;
  #pragma unroll
  for (int mi = 0; mi < 2; mi++){
    const size_t tok = tb + mi*16 + c;
    f32x4 d1 = {0,0,0,0}, d2 = {0,0,0,0};
    #pragma unroll
    for (int kc = 0; kc < 4; kc++){
      const f16x8 gof = ld8(Go + tok*128 + kc*32 + q4*8) *
                        *(const f16x8*)&upb[(mi*16 + c)*140 + kc*32 + q4*8];
      d1 = MFMA16(ld8(Wot + (size_t)(w*16 + c)*128 + kc*32 + q4*8), gof, d1);
    }
    #pragma unroll
    for (int kc = 0; kc < 8; kc++)
      d2 = MFMA16(ld8(Wbt + (size_t)(w*16 + c)*256 + kc*32 + q4*8),
                  ld8(T + tok*256 + kc*32 + q4*8), d2);
    const f16x4 glv = *(const f16x4*)&GL[tok*128 + w*16 + q4*4];
    const f16x4 gsv = *(const f16x4*)&GS[tok*128 + w*16 + q4*4];
    float4 o;
    o.x = (float)glv[0]*d1[0] + (float)gsv[0]*d2[0];
    o.y = (float)glv[1]*d1[1] + (float)gsv[1]*d2[1];
    o.z = (float)glv[2]*d1[2] + (float)gsv[2]*d2[2];
    o.w = (float)glv[3]*d1[3] + (float)gsv[3]*d2[3];
    *(float4*)&out[tok*128 + w*16 + q4*4] = o;
  }
}

// ---------------------------------------------------------------------------
extern "C" void kernel_launch(void* const* d_in, const int* in_sizes, int n_in,
                              void* d_out, int out_size, void* d_ws, size_t ws_size,
                              hipStream_t stream)
{
  (void)in_sizes; (void)n_in; (void)out_size; (void)ws_size;
  const float* a        = (const float*)d_in[0];
  const float* s        = (const float*)d_in[1];
  const float* z        = (const float*)d_in[2];
  const float* apb_gamma= (const float*)d_in[3];
  const float* apb_Wg   = (const float*)d_in[4];
  const float* apb_bg   = (const float*)d_in[5];
  const float* apb_Wskip= (const float*)d_in[6];
  const float* Wq       = (const float*)d_in[7];
  const float* bq       = (const float*)d_in[8];
  const float* Wk       = (const float*)d_in[9];
  const float* Wv       = (const float*)d_in[10];
  const float* Wgate    = (const float*)d_in[11];
  const float* Wo       = (const float*)d_in[12];
  const float* gamma_z  = (const float*)d_in[13];
  const float* Wz       = (const float*)d_in[14];
  const float* Wsl      = (const float*)d_in[15];
  const float* bsl      = (const float*)d_in[16];
  const float* ct_gamma = (const float*)d_in[17];
  const float* ct_Wg    = (const float*)d_in[18];
  const float* ct_bg    = (const float*)d_in[19];
  const float* ct_Wskip = (const float*)d_in[20];
  const float* Wa1      = (const float*)d_in[21];
  const float* Wa2      = (const float*)d_in[22];
  const float* Wb       = (const float*)d_in[23];
  const float* Wss      = (const float*)d_in[24];
  const float* bss      = (const float*)d_in[25];

  f16* W0 = (f16*)d_ws;
  const size_t SL = (size_t)32768*128;
  f16* qv = W0 + 0*SL;
  f16* kv = W0 + 1*SL;
  f16* vt = W0 + 2*SL;
  f16* gv = W0 + 3*SL;
  f16* tv = W0 + 4*SL;    // 2 slots (32768 x 256)
  f16* gl = W0 + 6*SL;
  f16* gs = W0 + 7*SL;
  f16* biasG = W0 + 8*SL; // 4 slots! (1024 tiles x 4 h x 32 q x 128 k = 16.78M f16)
  f16* wA  = W0 + 12*SL;
  f16* wC  = wA  + 256*128;
  f16* wQK = wC  + 256*128;
  f16* wVG = wQK + 256*128;
  f16* wSG = wVG + 256*128;
  f16* wAB = wSG + 256*128;
  f16* wO  = wAB + 512*128;
  f16* wBt = wO  + 128*128;
  float* wzg = (float*)(wBt + 128*256);
  float* Slv = wzg + 64;
  float* Ssv = Slv + 128;

  k_prep<<<dim3(128),256,0,stream>>>(apb_gamma,apb_Wg,apb_Wskip, ct_gamma,ct_Wg,ct_Wskip,
      Wq,Wk,Wv,Wgate, Wsl,Wss, Wa1,Wa2, Wo,Wb, gamma_z,Wz,
      wA,wC,wQK,wVG,wSG,wAB,wO,wBt,wzg,Slv,Ssv);
  k_pre<<<dim3(3072),256,0,stream>>>(a,s, z,wzg, wA,wC,wQK,wVG,wSG,wAB,
      apb_bg,ct_bg,bq,bsl,bss,Slv,Ssv, qv,kv,vt,gv,tv,gl,gs, biasG);
  k_attn<<<dim3(1024),512,0,stream>>>(qv,kv,vt,biasG, gv,tv,wO,wBt,gl,gs,(float*)d_out);
}

// Round 5
// 533.386 us; speedup vs baseline: 1.1798x; 1.1798x over previous
//
#include <hip/hip_runtime.h>

typedef _Float16 f16;
typedef f16 f16x8 __attribute__((ext_vector_type(8)));
typedef f16 f16x4 __attribute__((ext_vector_type(4)));
typedef f16 f16x2 __attribute__((ext_vector_type(2)));
typedef float f32x4 __attribute__((ext_vector_type(4)));

#define MFMA16(a,b,c) __builtin_amdgcn_mfma_f32_16x16x32_f16((a),(b),(c),0,0,0)

static __device__ __forceinline__ f16x8 ld8(const f16* p){ return *(const f16x8*)p; }
static __device__ __forceinline__ float sigm(float x){ return 1.f/(1.f + __expf(-x)); }

// ---------------------------------------------------------------------------
// Weight prep: fold gammas, cast fp16, store transposed (N rows x K cols) so
// B-fragments are contiguous 16B along K. Also colsums of Wsl/Wss for the
// raw-s gate un-normalization trick (4-way parallel + shuffle-reduced), and
// the fused gamma_z*Wz vector.
// ---------------------------------------------------------------------------
__global__ __launch_bounds__(256) void k_prep(
    const float* __restrict__ apb_gamma, const float* __restrict__ apb_Wg, const float* __restrict__ apb_Wskip,
    const float* __restrict__ ct_gamma,  const float* __restrict__ ct_Wg,  const float* __restrict__ ct_Wskip,
    const float* __restrict__ Wq, const float* __restrict__ Wk, const float* __restrict__ Wv, const float* __restrict__ Wgate,
    const float* __restrict__ Wsl, const float* __restrict__ Wss,
    const float* __restrict__ Wa1, const float* __restrict__ Wa2,
    const float* __restrict__ Wo, const float* __restrict__ Wb,
    const float* __restrict__ gamma_z, const float* __restrict__ Wz,
    f16* __restrict__ wA, f16* __restrict__ wC, f16* __restrict__ wQK, f16* __restrict__ wVG,
    f16* __restrict__ wSG, f16* __restrict__ wAB, f16* __restrict__ wO, f16* __restrict__ wBt,
    float* __restrict__ wzg, float* __restrict__ Slv, float* __restrict__ Ssv)
{
  const int t0 = blockIdx.x*256 + threadIdx.x;
  const int stride = gridDim.x*256;
  for (int i = t0; i < 256*128; i += stride){
    const int n = i >> 7, k = i & 127;
    const int m = n & 127;
    wA[i]  = (f16)(((n<128) ? apb_Wg[k*128+m] : apb_Wskip[k*128+m]) * apb_gamma[k]);
    wC[i]  = (f16)(((n<128) ? ct_Wg[k*128+m]  : ct_Wskip[k*128+m])  * ct_gamma[k]);
    wQK[i] = (f16)((n<128) ? Wq[k*128+m] : Wk[k*128+m]);
    wVG[i] = (f16)((n<128) ? Wv[k*128+m] : Wgate[k*128+m]);
    wSG[i] = (f16)((n<128) ? Wsl[k*128+m] : Wss[k*128+m]);
  }
  for (int i = t0; i < 512*128; i += stride){
    const int n = i >> 7, k = i & 127;
    wAB[i] = (f16)((n < 256) ? Wa1[k*256 + n] : Wa2[k*256 + (n-256)]);
  }
  for (int i = t0; i < 128*128; i += stride){
    const int n = i >> 7, k = i & 127;
    wO[i] = (f16)Wo[k*128+n];
  }
  for (int i = t0; i < 128*256; i += stride){
    const int n = i >> 8, k = i & 255;
    wBt[i] = (f16)Wb[k*128+n];
  }
  if (t0 < 64) wzg[t0] = gamma_z[t0 & 15] * Wz[(t0 & 15)*4 + (t0 >> 4)];
  if (t0 < 1024){
    const int mat = t0 >> 9;               // 0: Wsl, 1: Wss
    const int j = t0 & 511;
    const int cc = j >> 2, part = j & 3;   // 4 threads per column
    const float* Wp = mat ? Wss : Wsl;
    float acc = 0.f;
    #pragma unroll 4
    for (int k = part*32; k < part*32 + 32; k++) acc += Wp[k*128 + cc];
    acc += __shfl_xor(acc, 1);
    acc += __shfl_xor(acc, 2);
    if (part == 0){ if (mat) Ssv[cc] = acc; else Slv[cc] = acc; }
  }
}

// ---------------------------------------------------------------------------
// MEGA-FUSED pre-attention kernel. 64 rows per block, 256 threads (4 waves).
// Phase 1: LN(a), LN(s) -> LDS (f16) + per-row s mean/std.
// Phase 2: dual adaLN -> a1, a3 in LDS.
// Phase 3: QKVG (from a1), transition t (from a3), gates gl/gs (from sn,
//          un-normalized via std/mean + colsum). Outputs straight to global.
// LDS ~70 KB -> 2 blocks/CU. Weights stay hot in L1/L2.
// ---------------------------------------------------------------------------
__global__ __launch_bounds__(256) void k_pre(
    const float* __restrict__ A, const float* __restrict__ S,
    const f16* __restrict__ wA, const f16* __restrict__ wC,
    const f16* __restrict__ wQK, const f16* __restrict__ wVG,
    const f16* __restrict__ wSG, const f16* __restrict__ wAB,
    const float* __restrict__ bgA, const float* __restrict__ bgC,
    const float* __restrict__ bq, const float* __restrict__ bsl, const float* __restrict__ bss,
    const float* __restrict__ Slv, const float* __restrict__ Ssv,
    f16* __restrict__ Qo, f16* __restrict__ Ko, f16* __restrict__ Vt, f16* __restrict__ Go,
    f16* __restrict__ T, f16* __restrict__ GL, f16* __restrict__ GS)
{
  __shared__ f16 lsn[64*136];
  __shared__ f16 lan[64*136];
  __shared__ f16 la1[64*136];
  __shared__ f16 la3[64*136];
  __shared__ float lsm[64], lsd[64];
  const int tid = threadIdx.x;
  const size_t rbase = (size_t)blockIdx.x * 64;

  // ---- Phase 1: LayerNorm ----
  {
    const int row = tid >> 2, part = tid & 3;
    const size_t gr = rbase + row;
    // s
    {
      const float* sp = S + gr*128 + part*32;
      float v[32];
      #pragma unroll
      for (int j = 0; j < 8; j++){
        const float4 t4 = ((const float4*)sp)[j];
        v[j*4+0]=t4.x; v[j*4+1]=t4.y; v[j*4+2]=t4.z; v[j*4+3]=t4.w;
      }
      float sm = 0.f, sq = 0.f;
      #pragma unroll
      for (int j = 0; j < 32; j++){ sm += v[j]; sq += v[j]*v[j]; }
      sm += __shfl_xor(sm,1); sq += __shfl_xor(sq,1);
      sm += __shfl_xor(sm,2); sq += __shfl_xor(sq,2);
      const float mean = sm*(1.f/128.f);
      const float var  = sq*(1.f/128.f) - mean*mean;
      const float rstd = rsqrtf(var + 1e-5f);
      if (part == 0){ lsm[row] = mean; lsd[row] = (var + 1e-5f)*rstd; }  // std
      #pragma unroll
      for (int j = 0; j < 4; j++){
        f16x8 o;
        #pragma unroll
        for (int e = 0; e < 8; e++) o[e] = (f16)((v[j*8+e]-mean)*rstd);
        *(f16x8*)&lsn[row*136 + part*32 + j*8] = o;
      }
    }
    // a
    {
      const float* ap = A + gr*128 + part*32;
      float v[32];
      #pragma unroll
      for (int j = 0; j < 8; j++){
        const float4 t4 = ((const float4*)ap)[j];
        v[j*4+0]=t4.x; v[j*4+1]=t4.y; v[j*4+2]=t4.z; v[j*4+3]=t4.w;
      }
      float sm = 0.f, sq = 0.f;
      #pragma unroll
      for (int j = 0; j < 32; j++){ sm += v[j]; sq += v[j]*v[j]; }
      sm += __shfl_xor(sm,1); sq += __shfl_xor(sq,1);
      sm += __shfl_xor(sm,2); sq += __shfl_xor(sq,2);
      const float mean = sm*(1.f/128.f);
      const float var  = sq*(1.f/128.f) - mean*mean;
      const float rstd = rsqrtf(var + 1e-5f);
      #pragma unroll
      for (int j = 0; j < 4; j++){
        f16x8 o;
        #pragma unroll
        for (int e = 0; e < 8; e++) o[e] = (f16)((v[j*8+e]-mean)*rstd);
        *(f16x8*)&lan[row*136 + part*32 + j*8] = o;
      }
    }
  }
  __syncthreads();

  const int l = tid & 63, w = tid >> 6;
  const int c = l & 15, q4 = l >> 4;

  // ---- Phase 2: dual adaLN (16 wave-jobs: 8 col-tiles x {A,C}) ----
  for (int jj = 0; jj < 4; jj++){
    const int job = jj*4 + w;
    const int n0 = (job >> 1)*16;
    const int mat = job & 1;
    const f16* W = mat ? wC : wA;
    f16* dst = mat ? la3 : la1;
    const float bv = (mat ? bgC : bgA)[n0 + c];
    f16x8 b0[4], b1[4];
    #pragma unroll
    for (int kc = 0; kc < 4; kc++){
      b0[kc] = ld8(W + (size_t)(n0 + c)*128 + kc*32 + q4*8);
      b1[kc] = ld8(W + (size_t)(128 + n0 + c)*128 + kc*32 + q4*8);
    }
    for (int mi = 0; mi < 4; mi++){
      f32x4 d0 = {0,0,0,0}, d1 = {0,0,0,0};
      #pragma unroll
      for (int kc = 0; kc < 4; kc++){
        const f16x8 av = *(const f16x8*)&lsn[(mi*16 + c)*136 + kc*32 + q4*8];
        d0 = MFMA16(av, b0[kc], d0);
        d1 = MFMA16(av, b1[kc], d1);
      }
      #pragma unroll
      for (int r = 0; r < 4; r++){
        const int row = mi*16 + q4*4 + r;
        const float anv = (float)lan[row*136 + n0 + c];
        dst[row*136 + n0 + c] = (f16)(sigm(d0[r] + bv)*anv + d1[r]);
      }
    }
  }
  __syncthreads();

  // ---- Phase 3a: QKVG from a1 (8 wave-jobs) ----
  for (int jj = 0; jj < 2; jj++){
    const int n0 = (jj*4 + w)*16;
    f16x8 bQ[4], bK[4], bV[4], bG[4];
    #pragma unroll
    for (int kc = 0; kc < 4; kc++){
      bQ[kc] = ld8(wQK + (size_t)(n0 + c)*128 + kc*32 + q4*8);
      bK[kc] = ld8(wQK + (size_t)(128 + n0 + c)*128 + kc*32 + q4*8);
      bV[kc] = ld8(wVG + (size_t)(n0 + c)*128 + kc*32 + q4*8);
      bG[kc] = ld8(wVG + (size_t)(128 + n0 + c)*128 + kc*32 + q4*8);
    }
    const float bvq = bq[n0 + c];
    for (int mi = 0; mi < 4; mi++){
      f32x4 dQ = {0,0,0,0}, dK = {0,0,0,0}, dV = {0,0,0,0}, dG = {0,0,0,0};
      #pragma unroll
      for (int kc = 0; kc < 4; kc++){
        const f16x8 av = *(const f16x8*)&la1[(mi*16 + c)*136 + kc*32 + q4*8];
        dQ = MFMA16(av, bQ[kc], dQ);
        dK = MFMA16(av, bK[kc], dK);
        dV = MFMA16(av, bV[kc], dV);
        dG = MFMA16(av, bG[kc], dG);
      }
      #pragma unroll
      for (int r = 0; r < 4; r++){
        const size_t grow = rbase + mi*16 + q4*4 + r;
        Qo[grow*128 + n0 + c] = (f16)((dQ[r] + bvq)*0.17677669529663687f);
        Ko[grow*128 + n0 + c] = (f16)dK[r];
        Go[grow*128 + n0 + c] = (f16)sigm(dG[r]);
      }
      f16x4 vv;
      #pragma unroll
      for (int r = 0; r < 4; r++) vv[r] = (f16)dV[r];
      const int bidx = (int)(rbase >> 14);
      const int ntk  = (int)(rbase & 16383) + mi*16 + q4*4;
      *(f16x4*)(Vt + ((size_t)bidx*128 + n0 + c)*16384 + ntk) = vv;
    }
  }

  // ---- Phase 3b: transition t = silu(a3@Wa1) * (a3@Wa2) (16 wave-jobs) ----
  for (int jj = 0; jj < 4; jj++){
    const int n0t = (jj*4 + w)*16;
    f16x8 b1v[4], b2v[4];
    #pragma unroll
    for (int kc = 0; kc < 4; kc++){
      b1v[kc] = ld8(wAB + (size_t)(n0t + c)*128 + kc*32 + q4*8);
      b2v[kc] = ld8(wAB + (size_t)(256 + n0t + c)*128 + kc*32 + q4*8);
    }
    for (int mi = 0; mi < 4; mi++){
      f32x4 d0 = {0,0,0,0}, d1 = {0,0,0,0};
      #pragma unroll
      for (int kc = 0; kc < 4; kc++){
        const f16x8 av = *(const f16x8*)&la3[(mi*16 + c)*136 + kc*32 + q4*8];
        d0 = MFMA16(av, b1v[kc], d0);
        d1 = MFMA16(av, b2v[kc], d1);
      }
      #pragma unroll
      for (int r = 0; r < 4; r++){
        const size_t grow = rbase + mi*16 + q4*4 + r;
        const float u = d0[r];
        T[grow*256 + n0t + c] = (f16)((u*sigm(u))*d1[r]);
      }
    }
  }

  // ---- Phase 3c: gates from sn via un-normalization (8 wave-jobs) ----
  for (int jj = 0; jj < 2; jj++){
    const int n0 = (jj*4 + w)*16;
    f16x8 b0[4], b1[4];
    #pragma unroll
    for (int kc = 0; kc < 4; kc++){
      b0[kc] = ld8(wSG + (size_t)(n0 + c)*128 + kc*32 + q4*8);
      b1[kc] = ld8(wSG + (size_t)(128 + n0 + c)*128 + kc*32 + q4*8);
    }
    const float slc = Slv[n0 + c], ssc = Ssv[n0 + c];
    const float bl = bsl[n0 + c],  bs2 = bss[n0 + c];
    for (int mi = 0; mi < 4; mi++){
      f32x4 d0 = {0,0,0,0}, d1 = {0,0,0,0};
      #pragma unroll
      for (int kc = 0; kc < 4; kc++){
        const f16x8 av = *(const f16x8*)&lsn[(mi*16 + c)*136 + kc*32 + q4*8];
        d0 = MFMA16(av, b0[kc], d0);
        d1 = MFMA16(av, b1[kc], d1);
      }
      #pragma unroll
      for (int r = 0; r < 4; r++){
        const int row = mi*16 + q4*4 + r;
        const size_t grow = rbase + row;
        const float mn = lsm[row], sd = lsd[row];
        GL[grow*128 + n0 + c] = (f16)sigm(d0[r]*sd + mn*slc + bl);
        GS[grow*128 + n0 + c] = (f16)sigm(d1[r]*sd + mn*ssc + bs2);
      }
    }
  }
}

// ---------------------------------------------------------------------------
// Fused windowed attention, z-bias in-kernel (unchanged from round 2).
// ---------------------------------------------------------------------------
__global__ __launch_bounds__(512) void k_attn(const f16* __restrict__ Q, const f16* __restrict__ K,
    const f16* __restrict__ VT, const float* __restrict__ Z, const float* __restrict__ WZG,
    f16* __restrict__ Og)
{
  __shared__ f16 upb[17408];
  __shared__ float wzg_s[64];
  const int tid = threadIdx.x;
  const int b = blockIdx.x >> 9, nb = blockIdx.x & 511;
  if (tid < 64) wzg_s[tid] = WZG[tid];
  __syncthreads();
  #pragma unroll
  for (int i = 0; i < 8; i++){
    const int p  = tid + i*512;
    const int qq = p >> 7, kk = p & 127;
    const float* zp = Z + ((((size_t)b*512 + nb)*32 + qq)*128 + kk)*16;
    const float4 z0 = *(const float4*)(zp);
    const float4 z1 = *(const float4*)(zp + 4);
    const float4 z2 = *(const float4*)(zp + 8);
    const float4 z3 = *(const float4*)(zp + 12);
    const float xs[16] = {z0.x,z0.y,z0.z,z0.w, z1.x,z1.y,z1.z,z1.w,
                          z2.x,z2.y,z2.z,z2.w, z3.x,z3.y,z3.z,z3.w};
    float sm = 0.f, sq = 0.f;
    #pragma unroll
    for (int cc = 0; cc < 16; cc++){ sm += xs[cc]; sq += xs[cc]*xs[cc]; }
    const float mean = sm*(1.f/16.f);
    const float var  = sq*(1.f/16.f) - mean*mean;
    const float rs   = rsqrtf(var + 1e-5f);
    #pragma unroll
    for (int h = 0; h < 4; h++){
      float acc = 0.f;
      #pragma unroll
      for (int cc = 0; cc < 16; cc++) acc += (xs[cc]-mean)*wzg_s[h*16+cc];
      upb[(h*32 + qq)*132 + kk] = (f16)(acc*rs);
    }
  }
  __syncthreads();

  const int l = tid & 63, w = tid >> 6;
  const int c = l & 15, q4 = l >> 4;
  const int h = w >> 1, qh = w & 1, m0 = qh*16;
  const f16x8 aq = ld8(Q + ((size_t)b*16384 + (size_t)nb*32 + m0 + c)*128 + h*32 + q4*8);
  const long kbase = (long)b*16384 + (long)nb*32 - 48;
  f32x4 sc[8];
  #pragma unroll
  for (int nt = 0; nt < 8; nt++){
    const f16x8 bf = ld8(K + (kbase + nt*16 + c)*128 + h*32 + q4*8);
    f32x4 zz = {0.f,0.f,0.f,0.f};
    sc[nt] = MFMA16(aq, bf, zz);
  }
  #pragma unroll
  for (int nt = 0; nt < 8; nt++){
    const int key = nt*16 + c;
    const long kt = (long)nb*32 - 48 + key;
    const bool inv = (kt < 0) || (kt >= 16384);
    #pragma unroll
    for (int r = 0; r < 4; r++){
      const float v = sc[nt][r] + (float)upb[(h*32 + m0 + q4*4 + r)*132 + key];
      sc[nt][r] = inv ? -1e9f : v;
    }
  }
  #pragma unroll
  for (int r = 0; r < 4; r++){
    float mx = sc[0][r];
    #pragma unroll
    for (int nt = 1; nt < 8; nt++) mx = fmaxf(mx, sc[nt][r]);
    #pragma unroll
    for (int o = 8; o; o >>= 1) mx = fmaxf(mx, __shfl_xor(mx, o));
    float sum = 0.f;
    #pragma unroll
    for (int nt = 0; nt < 8; nt++){ const float e = __expf(sc[nt][r]-mx); sc[nt][r] = e; sum += e; }
    #pragma unroll
    for (int o = 8; o; o >>= 1) sum += __shfl_xor(sum, o);
    const float inv = 1.f/sum;
    #pragma unroll
    for (int nt = 0; nt < 8; nt++) sc[nt][r] *= inv;
  }
  __syncthreads();
  #pragma unroll
  for (int nt = 0; nt < 8; nt++)
    #pragma unroll
    for (int r = 0; r < 4; r++)
      upb[(w*16 + q4*4 + r)*136 + nt*16 + c] = (f16)sc[nt][r];
  const f16* vb = VT + ((long)b*128)*16384 + (long)nb*32 - 48;
  f32x4 o0 = {0.f,0.f,0.f,0.f}, o1 = {0.f,0.f,0.f,0.f};
  #pragma unroll
  for (int kc = 0; kc < 4; kc++){
    const f16x8 pa = *(const f16x8*)&upb[(w*16 + c)*136 + kc*32 + q4*8];
    const f16x8 v0 = ld8(vb + (long)(h*32 + c)*16384 + kc*32 + q4*8);
    const f16x8 v1 = ld8(vb + (long)(h*32 + 16 + c)*16384 + kc*32 + q4*8);
    o0 = MFMA16(pa, v0, o0);
    o1 = MFMA16(pa, v1, o1);
  }
  #pragma unroll
  for (int r = 0; r < 4; r++){
    const size_t tok = (size_t)b*16384 + (size_t)nb*32 + m0 + q4*4 + r;
    Og[tok*128 + h*32 + c]      = (f16)o0[r];
    Og[tok*128 + h*32 + 16 + c] = (f16)o1[r];
  }
}

// ---------------------------------------------------------------------------
// Final: out = gl*((g.o)@Wo) + gs*(t@Wb). 64 rows/block; A-frags loaded once,
// all 8 col-tiles looped in-block (B stays L1/L2-hot) -> G/O/T read ONCE.
// ---------------------------------------------------------------------------
__global__ __launch_bounds__(256) void k_final(const f16* __restrict__ G, const f16* __restrict__ O,
    const f16* __restrict__ T, const f16* __restrict__ Wot, const f16* __restrict__ Wbt,
    const f16* __restrict__ GL, const f16* __restrict__ GS, float* __restrict__ out)
{
  const int l = threadIdx.x & 63, w = threadIdx.x >> 6;
  const int c = l & 15, q4 = l >> 4;
  const int mbase = blockIdx.x*64 + w*16;
  f16x8 ag[4], at[8];
  const f16* gp = G + (size_t)(mbase + c)*128 + q4*8;
  const f16* op = O + (size_t)(mbase + c)*128 + q4*8;
  #pragma unroll
  for (int kc = 0; kc < 4; kc++) ag[kc] = ld8(gp + kc*32) * ld8(op + kc*32);
  const f16* tp = T + (size_t)(mbase + c)*256 + q4*8;
  #pragma unroll
  for (int kc = 0; kc < 8; kc++) at[kc] = ld8(tp + kc*32);
  for (int nt = 0; nt < 8; nt++){
    const int cb = nt*16;
    f32x4 d1 = {0,0,0,0}, d2 = {0,0,0,0};
    #pragma unroll
    for (int kc = 0; kc < 4; kc++)
      d1 = MFMA16(ag[kc], ld8(Wot + (size_t)(cb + c)*128 + kc*32 + q4*8), d1);
    #pragma unroll
    for (int kc = 0; kc < 8; kc++)
      d2 = MFMA16(at[kc], ld8(Wbt + (size_t)(cb + c)*256 + kc*32 + q4*8), d2);
    #pragma unroll
    for (int r = 0; r < 4; r++){
      const size_t row = mbase + q4*4 + r;
      const float glv = (float)GL[row*128 + cb + c];
      const float gsv = (float)GS[row*128 + cb + c];
      out[row*128 + cb + c] = glv*d1[r] + gsv*d2[r];
    }
  }
}

// ---------------------------------------------------------------------------
extern "C" void kernel_launch(void* const* d_in, const int* in_sizes, int n_in,
                              void* d_out, int out_size, void* d_ws, size_t ws_size,
                              hipStream_t stream)
{
  (void)in_sizes; (void)n_in; (void)out_size; (void)ws_size;
  const float* a        = (const float*)d_in[0];
  const float* s        = (const float*)d_in[1];
  const float* z        = (const float*)d_in[2];
  const float* apb_gamma= (const float*)d_in[3];
  const float* apb_Wg   = (const float*)d_in[4];
  const float* apb_bg   = (const float*)d_in[5];
  const float* apb_Wskip= (const float*)d_in[6];
  const float* Wq       = (const float*)d_in[7];
  const float* bq       = (const float*)d_in[8];
  const float* Wk       = (const float*)d_in[9];
  const float* Wv       = (const float*)d_in[10];
  const float* Wgate    = (const float*)d_in[11];
  const float* Wo       = (const float*)d_in[12];
  const float* gamma_z  = (const float*)d_in[13];
  const float* Wz       = (const float*)d_in[14];
  const float* Wsl      = (const float*)d_in[15];
  const float* bsl      = (const float*)d_in[16];
  const float* ct_gamma = (const float*)d_in[17];
  const float* ct_Wg    = (const float*)d_in[18];
  const float* ct_bg    = (const float*)d_in[19];
  const float* ct_Wskip = (const float*)d_in[20];
  const float* Wa1      = (const float*)d_in[21];
  const float* Wa2      = (const float*)d_in[22];
  const float* Wb       = (const float*)d_in[23];
  const float* Wss      = (const float*)d_in[24];
  const float* bss      = (const float*)d_in[25];

  f16* W0 = (f16*)d_ws;
  const size_t SL = (size_t)32768*128;
  f16* qv = W0 + 0*SL;
  f16* kv = W0 + 1*SL;
  f16* vt = W0 + 2*SL;
  f16* gv = W0 + 3*SL;
  f16* tv = W0 + 4*SL;   // 2 slots (32768 x 256)
  f16* gl = W0 + 6*SL;
  f16* gs = W0 + 7*SL;
  f16* ov = W0 + 8*SL;
  f16* wA  = W0 + 9*SL;
  f16* wC  = wA  + 256*128;
  f16* wQK = wC  + 256*128;
  f16* wVG = wQK + 256*128;
  f16* wSG = wVG + 256*128;
  f16* wAB = wSG + 256*128;
  f16* wO  = wAB + 512*128;
  f16* wBt = wO  + 128*128;
  float* wzg = (float*)(wBt + 128*256);
  float* Slv = wzg + 64;
  float* Ssv = Slv + 128;

  k_prep<<<dim3(64),256,0,stream>>>(apb_gamma,apb_Wg,apb_Wskip, ct_gamma,ct_Wg,ct_Wskip,
      Wq,Wk,Wv,Wgate, Wsl,Wss, Wa1,Wa2, Wo,Wb, gamma_z,Wz,
      wA,wC,wQK,wVG,wSG,wAB,wO,wBt,wzg,Slv,Ssv);
  k_pre<<<dim3(512),256,0,stream>>>(a,s, wA,wC,wQK,wVG,wSG,wAB,
      apb_bg,ct_bg,bq,bsl,bss,Slv,Ssv, qv,kv,vt,gv,tv,gl,gs);
  k_attn<<<dim3(1024),512,0,stream>>>(qv,kv,vt,z,wzg,ov);
  k_final<<<dim3(512),256,0,stream>>>(gv,ov,tv,wO,wBt,gl,gs,(float*)d_out);
}